// Round 4
// baseline (466.305 us; speedup 1.0000x reference)
//
#include <hip/hip_runtime.h>
#include <math.h>

#define T_LEN 512
#define B_N   1024
#define K_N   48
#define START_TAG (K_N - 2)
#define STOP_TAG  (K_N - 1)
#define NEG   -10000.0f

// One wave (64 threads) per batch; lane j owns state j (row j of E = exp(trans)).
// Scaled-exponential domain: q_j = exp(alpha_j - C).
//   s_j  = sum_{k<47} E[j,k] * q_k        (col 47 = STOP is exp(-1e4) = 0)
//   q'_j = F_j * inv * s_j,  F_j = exp(feat[t,b,j]), inv = 1/q_0, C += log(q_0)
// q broadcast: 47 v_readlane -> SGPRs. No LDS/memory in the recursion.
//
// __launch_bounds__(64, 1) is load-bearing: R3 showed that without the
// min-waves-per-EU=1 hint the allocator budgets 32 VGPRs and spills all of
// E to scratch (VGPR_Count=32, 356us). With 1024 waves on 1024 SIMDs we
// only ever get 1 wave/SIMD anyway, so trading occupancy for registers
// costs nothing.

#define REP47(M) M(0)M(1)M(2)M(3)M(4)M(5)M(6)M(7)M(8)M(9)M(10)M(11)M(12) \
  M(13)M(14)M(15)M(16)M(17)M(18)M(19)M(20)M(21)M(22)M(23)M(24)M(25)M(26) \
  M(27)M(28)M(29)M(30)M(31)M(32)M(33)M(34)M(35)M(36)M(37)M(38)M(39)M(40) \
  M(41)M(42)M(43)M(44)M(45)M(46)

__global__ __launch_bounds__(64, 1) void crf_fused_kernel(
    const float* __restrict__ feats,    // (T, B, K)
    const float* __restrict__ trans,    // (K, K)
    const int*   __restrict__ tags,     // (B, T)
    const int*   __restrict__ lengths,  // (B,)
    float* __restrict__ out)
{
    const int b    = blockIdx.x;
    const int lane = threadIdx.x;
    const int len  = lengths[b];

    // E row j in named scalars (VGPR-resident with the wide budget).
    // Lanes >= K_N: zeros, so their q stays 0 and is never readlane'd.
#define DECL_E(k) float E##k = (lane < K_N) ? __expf(trans[lane * K_N + k]) : 0.0f;
    REP47(DECL_E)
#undef DECL_E

    const float*  fb = feats + (size_t)b * K_N;
    const size_t  sT = (size_t)B_N * K_N;

    float q = (lane == START_TAG) ? 1.0f : 0.0f;
    float C = 0.0f;

    // Distance-4 raw-feat prefetch pipeline.
    float F_cur = __expf((lane < K_N) ? fb[lane] : 0.0f);
    float r1 = (1 < len && lane < K_N) ? fb[sT + lane]     : 0.0f;
    float r2 = (2 < len && lane < K_N) ? fb[2 * sT + lane] : 0.0f;
    float r3 = (3 < len && lane < K_N) ? fb[3 * sT + lane] : 0.0f;

    for (int t = 0; t < len; ++t) {
        // Broadcast q to wave-uniform values (SGPRs) via readlane.
#define DECL_S(k) float s##k = __uint_as_float(__builtin_amdgcn_readlane(__float_as_uint(q), k));
        REP47(DECL_S)
#undef DECL_S

        // Off-chain scalar work (overlaps with the FMA dot below).
        float inv, dC;
        if (s0 > 0.0f) { inv = 1.0f / s0; dC = __logf(s0); }  // false only at t==0
        else           { inv = 1.0f;      dC = 0.0f; }
        C += dC;
        float scale  = F_cur * inv;
        F_cur = __expf(r1);
        float rload = (t + 4 < len && lane < K_N) ? fb[(size_t)(t + 4) * sT + lane] : 0.0f;

        // 47-term dot, 4 accumulator chains.
        float a0 = 0.f, a1 = 0.f, a2 = 0.f, a3 = 0.f;
#define FMA4(k0,k1,k2,k3) \
        a0 = fmaf(E##k0, s##k0, a0); a1 = fmaf(E##k1, s##k1, a1); \
        a2 = fmaf(E##k2, s##k2, a2); a3 = fmaf(E##k3, s##k3, a3);
        FMA4(0,1,2,3)    FMA4(4,5,6,7)    FMA4(8,9,10,11)  FMA4(12,13,14,15)
        FMA4(16,17,18,19) FMA4(20,21,22,23) FMA4(24,25,26,27) FMA4(28,29,30,31)
        FMA4(32,33,34,35) FMA4(36,37,38,39) FMA4(40,41,42,43)
        a0 = fmaf(E44, s44, a0); a1 = fmaf(E45, s45, a1); a2 = fmaf(E46, s46, a2);
#undef FMA4
        float s = (a0 + a1) + (a2 + a3);

        q = s * scale;
        r1 = r2; r2 = r3; r3 = rload;
    }

    // log_z = C + log(q_j) + trans[STOP, j], logsumexp over lanes.
    float v = (lane < K_N && q > 0.0f)
            ? C + __logf(q) + trans[STOP_TAG * K_N + lane] : -INFINITY;
    float mz = v;
    #pragma unroll
    for (int off = 32; off >= 1; off >>= 1)
        mz = fmaxf(mz, __shfl_xor(mz, off));
    float e = __expf(v - mz);
    float se = e;
    #pragma unroll
    for (int off = 32; off >= 1; off >>= 1)
        se += __shfl_xor(se, off);
    float log_z = mz + __logf(se);

    // Gold path score: lanes stripe over t.
    float gsum = 0.0f;
    for (int t = lane; t < len; t += 64) {
        int next = tags[(size_t)b * T_LEN + t];
        int prev = (t == 0) ? START_TAG : tags[(size_t)b * T_LEN + t - 1];
        gsum += trans[next * K_N + prev]
              + fb[(size_t)t * sT + next];
    }
    #pragma unroll
    for (int off = 32; off >= 1; off >>= 1)
        gsum += __shfl_xor(gsum, off);

    if (lane == 0) {
        int last = tags[(size_t)b * T_LEN + len - 1];
        float gold = gsum + trans[STOP_TAG * K_N + last];
        atomicAdd(out, log_z - gold);
    }
}

extern "C" void kernel_launch(void* const* d_in, const int* in_sizes, int n_in,
                              void* d_out, int out_size, void* d_ws, size_t ws_size,
                              hipStream_t stream) {
    const float* feats   = (const float*)d_in[0];
    const float* trans   = (const float*)d_in[1];
    const int*   tags    = (const int*)d_in[2];
    const int*   lengths = (const int*)d_in[3];
    float* out = (float*)d_out;

    hipMemsetAsync(out, 0, sizeof(float) * out_size, stream);
    crf_fused_kernel<<<B_N, 64, 0, stream>>>(feats, trans, tags, lengths, out);
}

// Round 5
// 426.189 us; speedup vs baseline: 1.0941x; 1.0941x over previous
//
#include <hip/hip_runtime.h>
#include <math.h>

#define T_LEN 512
#define B_N   1024
#define K_N   48
#define START_TAG (K_N - 2)
#define STOP_TAG  (K_N - 1)
#define NEG   -10000.0f

// One wave (64 threads) per batch; lane j owns state j (row j of E = exp(trans)).
// Scaled-exponential domain: q_j = exp(alpha_j - C).
//   s_j  = sum_{k<47} E[j,k] * q_k        (col 47 = STOP is exp(-1e4) = 0)
//   q'_j = F_j * inv * s_j,  F_j = exp(feat[t,b,j]), inv = 1/q_0, C += log(q_0)
// q broadcast: 47 v_readlane -> SGPRs. No LDS/memory in the recursion.
//
// amdgpu_waves_per_eu(1,1) is the load-bearing change: R3/R4 showed the
// backend's occupancy heuristic budgets 32 VGPRs and keeps all 47 E values
// in scratch (47 L1 loads per step = the real bottleneck, ~1650 cy/step).
// With grid = 1024 waves on 1024 SIMDs we get exactly 1 wave/EU regardless,
// so pinning the compiler's occupancy target to 1 costs nothing and grants
// the full register file.

#define REP47(M) M(0)M(1)M(2)M(3)M(4)M(5)M(6)M(7)M(8)M(9)M(10)M(11)M(12) \
  M(13)M(14)M(15)M(16)M(17)M(18)M(19)M(20)M(21)M(22)M(23)M(24)M(25)M(26) \
  M(27)M(28)M(29)M(30)M(31)M(32)M(33)M(34)M(35)M(36)M(37)M(38)M(39)M(40) \
  M(41)M(42)M(43)M(44)M(45)M(46)

__global__ __launch_bounds__(64)
__attribute__((amdgpu_waves_per_eu(1, 1)))
void crf_fused_kernel(
    const float* __restrict__ feats,    // (T, B, K)
    const float* __restrict__ trans,    // (K, K)
    const int*   __restrict__ tags,     // (B, T)
    const int*   __restrict__ lengths,  // (B,)
    float* __restrict__ out)
{
    const int b    = blockIdx.x;
    const int lane = threadIdx.x;
    const int len  = lengths[b];

    // E row j in named scalars. Lanes >= K_N read row STOP (valid memory,
    // finite values) and compute junk q forever — harmless: those lanes are
    // never readlane'd (k <= 46) and never stored (epilogue masks lane<K_N).
    const int row = (lane < K_N) ? lane : (K_N - 1);
    const float* tr = trans + row * K_N;
#define DECL_E(k) float E##k = __expf(tr[k]);
    REP47(DECL_E)
#undef DECL_E

    const float*  fb = feats + (size_t)b * K_N;
    const size_t  sT = (size_t)B_N * K_N;

    float q = (lane == START_TAG) ? 1.0f : 0.0f;
    float C = 0.0f;

    // Distance-4 raw-feat prefetch pipeline.
    float F_cur = __expf((lane < K_N) ? fb[lane] : 0.0f);
    float r1 = (1 < len && lane < K_N) ? fb[sT + lane]     : 0.0f;
    float r2 = (2 < len && lane < K_N) ? fb[2 * sT + lane] : 0.0f;
    float r3 = (3 < len && lane < K_N) ? fb[3 * sT + lane] : 0.0f;

    for (int t = 0; t < len; ++t) {
        // Broadcast q to wave-uniform values (SGPRs) via readlane.
#define DECL_S(k) float s##k = __uint_as_float(__builtin_amdgcn_readlane(__float_as_uint(q), k));
        REP47(DECL_S)
#undef DECL_S

        // Off-chain scalar work (overlaps with the FMA dot below).
        float inv, dC;
        if (s0 > 0.0f) { inv = 1.0f / s0; dC = __logf(s0); }  // false only at t==0
        else           { inv = 1.0f;      dC = 0.0f; }
        C += dC;
        float scale  = F_cur * inv;
        F_cur = __expf(r1);
        float rload = (t + 4 < len && lane < K_N) ? fb[(size_t)(t + 4) * sT + lane] : 0.0f;

        // 47-term dot, 4 accumulator chains.
        float a0 = 0.f, a1 = 0.f, a2 = 0.f, a3 = 0.f;
#define FMA4(k0,k1,k2,k3) \
        a0 = fmaf(E##k0, s##k0, a0); a1 = fmaf(E##k1, s##k1, a1); \
        a2 = fmaf(E##k2, s##k2, a2); a3 = fmaf(E##k3, s##k3, a3);
        FMA4(0,1,2,3)    FMA4(4,5,6,7)    FMA4(8,9,10,11)  FMA4(12,13,14,15)
        FMA4(16,17,18,19) FMA4(20,21,22,23) FMA4(24,25,26,27) FMA4(28,29,30,31)
        FMA4(32,33,34,35) FMA4(36,37,38,39) FMA4(40,41,42,43)
        a0 = fmaf(E44, s44, a0); a1 = fmaf(E45, s45, a1); a2 = fmaf(E46, s46, a2);
#undef FMA4
        float s = (a0 + a1) + (a2 + a3);

        q = s * scale;
        r1 = r2; r2 = r3; r3 = rload;
    }

    // log_z = C + log(q_j) + trans[STOP, j], logsumexp over lanes.
    float v = (lane < K_N && q > 0.0f)
            ? C + __logf(q) + trans[STOP_TAG * K_N + lane] : -INFINITY;
    float mz = v;
    #pragma unroll
    for (int off = 32; off >= 1; off >>= 1)
        mz = fmaxf(mz, __shfl_xor(mz, off));
    float e = __expf(v - mz);
    float se = e;
    #pragma unroll
    for (int off = 32; off >= 1; off >>= 1)
        se += __shfl_xor(se, off);
    float log_z = mz + __logf(se);

    // Gold path score: lanes stripe over t.
    float gsum = 0.0f;
    for (int t = lane; t < len; t += 64) {
        int next = tags[(size_t)b * T_LEN + t];
        int prev = (t == 0) ? START_TAG : tags[(size_t)b * T_LEN + t - 1];
        gsum += trans[next * K_N + prev]
              + fb[(size_t)t * sT + next];
    }
    #pragma unroll
    for (int off = 32; off >= 1; off >>= 1)
        gsum += __shfl_xor(gsum, off);

    if (lane == 0) {
        int last = tags[(size_t)b * T_LEN + len - 1];
        float gold = gsum + trans[STOP_TAG * K_N + last];
        atomicAdd(out, log_z - gold);
    }
}

extern "C" void kernel_launch(void* const* d_in, const int* in_sizes, int n_in,
                              void* d_out, int out_size, void* d_ws, size_t ws_size,
                              hipStream_t stream) {
    const float* feats   = (const float*)d_in[0];
    const float* trans   = (const float*)d_in[1];
    const int*   tags    = (const int*)d_in[2];
    const int*   lengths = (const int*)d_in[3];
    float* out = (float*)d_out;

    hipMemsetAsync(out, 0, sizeof(float) * out_size, stream);
    crf_fused_kernel<<<B_N, 64, 0, stream>>>(feats, trans, tags, lengths, out);
}

// Round 6
// 346.079 us; speedup vs baseline: 1.3474x; 1.2315x over previous
//
#include <hip/hip_runtime.h>
#include <math.h>

#define T_LEN 512
#define B_N   1024
#define K_N   48
#define START_TAG (K_N - 2)
#define STOP_TAG  (K_N - 1)
#define NEG   -10000.0f

// One wave (64 threads) per batch; lane j owns state j (row j of E = exp(trans)).
// Scaled-exponential domain: q_j = exp(alpha_j - C).
//   s_j  = sum_{k<47} E[j,k] * q_k        (col 47 = STOP is exp(-1e4) = 0)
//   q'_j = F_j * inv * s_j,  F_j = exp(feat[t,b,j]), inv = 1/q_0, C += log(q_0)
// q broadcast: 47 v_readlane -> SGPRs.
//
// Load-bearing details (hard-won):
//  * amdgpu_waves_per_eu(1,1): without it the allocator budgets 32 VGPRs and
//    spills all of E to scratch (R3/R4). With it: VGPR_Count=132, E resident.
//  * The feat prefetch must be UNCONDITIONAL (indices clamped, no branch):
//    R1-R5 guarded it with `if (t+d < len && lane < K_N)`, which defeats
//    static vmcnt tracking -> compiler emits vmcnt(0) each step -> every
//    iteration eats a full ~1250cy HBM latency. That was the real bottleneck
//    (VALUBusy 15%, 1472 cy/step vs 220 cy of VALU issue).

#define REP47(M) M(0)M(1)M(2)M(3)M(4)M(5)M(6)M(7)M(8)M(9)M(10)M(11)M(12) \
  M(13)M(14)M(15)M(16)M(17)M(18)M(19)M(20)M(21)M(22)M(23)M(24)M(25)M(26) \
  M(27)M(28)M(29)M(30)M(31)M(32)M(33)M(34)M(35)M(36)M(37)M(38)M(39)M(40) \
  M(41)M(42)M(43)M(44)M(45)M(46)

__global__ __launch_bounds__(64)
__attribute__((amdgpu_waves_per_eu(1, 1)))
void crf_fused_kernel(
    const float* __restrict__ feats,    // (T, B, K)
    const float* __restrict__ trans,    // (K, K)
    const int*   __restrict__ tags,     // (B, T)
    const int*   __restrict__ lengths,  // (B,)
    float* __restrict__ out)
{
    const int b      = blockIdx.x;
    const int lane   = threadIdx.x;
    const int len    = lengths[b];
    const int lane_c = (lane < K_N) ? lane : (K_N - 1);   // clamp: all addrs valid

    // E row in named scalars (VGPR-resident). Lanes >= K_N compute a junk
    // (but finite, bounded) q forever — harmless: never readlane'd (k<=46),
    // never stored (epilogue masks lane < K_N).
    const float* tr = trans + lane_c * K_N;
#define DECL_E(k) float E##k = __expf(tr[k]);
    REP47(DECL_E)
#undef DECL_E

    const float*  fb = feats + (size_t)b * K_N;
    const size_t  sT = (size_t)B_N * K_N;

    float q = (lane == START_TAG) ? 1.0f : 0.0f;
    float C = 0.0f;

    // Distance-6 prefetch pipeline, all loads unconditional with clamped
    // time index (feats values are finite everywhere, so junk-but-valid
    // reads past len are safe; they are never consumed).
    auto rowclamp = [len](int t) { int m = len - 1; return t < m ? t : m; };
    float F_cur = __expf(fb[lane_c]);                       // feat[0], len >= 1
    float r1 = fb[(size_t)rowclamp(1) * sT + lane_c];
    float r2 = fb[(size_t)rowclamp(2) * sT + lane_c];
    float r3 = fb[(size_t)rowclamp(3) * sT + lane_c];
    float r4 = fb[(size_t)rowclamp(4) * sT + lane_c];
    float r5 = fb[(size_t)rowclamp(5) * sT + lane_c];

    for (int t = 0; t < len; ++t) {
        // Unconditional prefetch of row t+6 (clamped) — issued first so the
        // compiler can wait with vmcnt(N>0) when r1 is consumed below.
        float rload = fb[(size_t)rowclamp(t + 6) * sT + lane_c];

        // Broadcast q to wave-uniform values (SGPRs) via readlane.
#define DECL_S(k) float s##k = __uint_as_float(__builtin_amdgcn_readlane(__float_as_uint(q), k));
        REP47(DECL_S)
#undef DECL_S

        // Off-chain scalar work, branchless (s0 == 0 only at t == 0).
        bool  live = (s0 > 0.0f);
        float inv  = live ? (1.0f / s0) : 1.0f;
        C         += live ? __logf(s0)  : 0.0f;
        float scale  = F_cur * inv;
        F_cur = __expf(r1);

        // 47-term dot, 4 accumulator chains.
        float a0 = 0.f, a1 = 0.f, a2 = 0.f, a3 = 0.f;
#define FMA4(k0,k1,k2,k3) \
        a0 = fmaf(E##k0, s##k0, a0); a1 = fmaf(E##k1, s##k1, a1); \
        a2 = fmaf(E##k2, s##k2, a2); a3 = fmaf(E##k3, s##k3, a3);
        FMA4(0,1,2,3)    FMA4(4,5,6,7)    FMA4(8,9,10,11)  FMA4(12,13,14,15)
        FMA4(16,17,18,19) FMA4(20,21,22,23) FMA4(24,25,26,27) FMA4(28,29,30,31)
        FMA4(32,33,34,35) FMA4(36,37,38,39) FMA4(40,41,42,43)
        a0 = fmaf(E44, s44, a0); a1 = fmaf(E45, s45, a1); a2 = fmaf(E46, s46, a2);
#undef FMA4
        float s = (a0 + a1) + (a2 + a3);

        q = s * scale;
        r1 = r2; r2 = r3; r3 = r4; r4 = r5; r5 = rload;
    }

    // log_z = C + log(q_j) + trans[STOP, j], logsumexp over lanes.
    float v = (lane < K_N && q > 0.0f)
            ? C + __logf(q) + trans[STOP_TAG * K_N + lane] : -INFINITY;
    float mz = v;
    #pragma unroll
    for (int off = 32; off >= 1; off >>= 1)
        mz = fmaxf(mz, __shfl_xor(mz, off));
    float e = __expf(v - mz);
    float se = e;
    #pragma unroll
    for (int off = 32; off >= 1; off >>= 1)
        se += __shfl_xor(se, off);
    float log_z = mz + __logf(se);

    // Gold path score: lanes stripe over t.
    float gsum = 0.0f;
    for (int t = lane; t < len; t += 64) {
        int next = tags[(size_t)b * T_LEN + t];
        int prev = (t == 0) ? START_TAG : tags[(size_t)b * T_LEN + t - 1];
        gsum += trans[next * K_N + prev]
              + fb[(size_t)t * sT + next];
    }
    #pragma unroll
    for (int off = 32; off >= 1; off >>= 1)
        gsum += __shfl_xor(gsum, off);

    if (lane == 0) {
        int last = tags[(size_t)b * T_LEN + len - 1];
        float gold = gsum + trans[STOP_TAG * K_N + last];
        atomicAdd(out, log_z - gold);
    }
}

extern "C" void kernel_launch(void* const* d_in, const int* in_sizes, int n_in,
                              void* d_out, int out_size, void* d_ws, size_t ws_size,
                              hipStream_t stream) {
    const float* feats   = (const float*)d_in[0];
    const float* trans   = (const float*)d_in[1];
    const int*   tags    = (const int*)d_in[2];
    const int*   lengths = (const int*)d_in[3];
    float* out = (float*)d_out;

    hipMemsetAsync(out, 0, sizeof(float) * out_size, stream);
    crf_fused_kernel<<<B_N, 64, 0, stream>>>(feats, trans, tags, lengths, out);
}

// Round 7
// 246.657 us; speedup vs baseline: 1.8905x; 1.4031x over previous
//
#include <hip/hip_runtime.h>
#include <math.h>

#define T_LEN 512
#define B_N   1024
#define K_N   48
#define START_TAG (K_N - 2)
#define STOP_TAG  (K_N - 1)
#define NEG   -10000.0f

// One wave (64 threads) per batch; lane j owns state j (row j of E = exp(trans)).
// Scaled-exponential domain: q_j = exp(alpha_j - C).
//   s_j  = sum_{k<47} E[j,k] * q_k        (col 47 = STOP is exp(-1e4) = 0)
//   q'_j = F_j * inv * s_j,  F_j = exp(feat[t,b,j]), inv = rcp(q_0), C += log(q_0)
// q broadcast: 47 v_readlane -> SGPRs. No LDS/memory on the recursion chain.
//
// Hard-won, load-bearing details:
//  * amdgpu_waves_per_eu(1,1): without it the allocator budgets 32 VGPRs and
//    spills E to scratch (R3/R4: 355us). With it VGPR_Count=132, E resident.
//  * Loads must be UNCONDITIONAL (clamped indices, no branch) — R5.
//  * NO register rotation in a rolled loop (R6): `r1=r2;...;r5=rload` is a
//    v_mov from the just-issued load's dest reg -> forces vmcnt(0) drain every
//    step -> full ~900cy HBM latency per step (measured 1111 cy/step, VALU
//    only 207). Fix: fixed 512-step trip, statically unrolled 8-step ping-pong
//    phases (f0/f1 arrays, static indices = pure renames), per-step `t<len`
//    cndmask guard reproduces the reference mask (freeze alpha) semantics.

#define REP47(M) M(0)M(1)M(2)M(3)M(4)M(5)M(6)M(7)M(8)M(9)M(10)M(11)M(12) \
  M(13)M(14)M(15)M(16)M(17)M(18)M(19)M(20)M(21)M(22)M(23)M(24)M(25)M(26) \
  M(27)M(28)M(29)M(30)M(31)M(32)M(33)M(34)M(35)M(36)M(37)M(38)M(39)M(40) \
  M(41)M(42)M(43)M(44)M(45)M(46)

#define DECL_S(k) float s##k = __uint_as_float(__builtin_amdgcn_readlane(__float_as_uint(q), k));

#define FMA4(k0,k1,k2,k3) \
        a0 = fmaf(E##k0, s##k0, a0); a1 = fmaf(E##k1, s##k1, a1); \
        a2 = fmaf(E##k2, s##k2, a2); a3 = fmaf(E##k3, s##k3, a3);

// One recursion step at time TT consuming raw feat value FVAL.
// Invariant alpha_j = C + log(q_j) is updated only when TT < len.
#define STEP(TT, FVAL) do { \
        REP47(DECL_S) \
        const bool  live = (s0 > 0.0f);                     /* false only at t==0 */ \
        const float inv  = live ? __builtin_amdgcn_rcpf(s0) : 1.0f; \
        const float dC   = live ? __logf(s0) : 0.0f; \
        const bool  on   = ((TT) < len); \
        C += on ? dC : 0.0f; \
        const float scale = __expf(FVAL) * inv; \
        float a0 = 0.f, a1 = 0.f, a2 = 0.f, a3 = 0.f; \
        FMA4(0,1,2,3)     FMA4(4,5,6,7)     FMA4(8,9,10,11)   FMA4(12,13,14,15) \
        FMA4(16,17,18,19) FMA4(20,21,22,23) FMA4(24,25,26,27) FMA4(28,29,30,31) \
        FMA4(32,33,34,35) FMA4(36,37,38,39) FMA4(40,41,42,43) \
        a0 = fmaf(E44, s44, a0); a1 = fmaf(E45, s45, a1); a2 = fmaf(E46, s46, a2); \
        const float ssum = (a0 + a1) + (a2 + a3); \
        q = on ? ssum * scale : q; \
    } while (0)

__global__ __launch_bounds__(64)
__attribute__((amdgpu_waves_per_eu(1, 1)))
void crf_fused_kernel(
    const float* __restrict__ feats,    // (T, B, K)
    const float* __restrict__ trans,    // (K, K)
    const int*   __restrict__ tags,     // (B, T)
    const int*   __restrict__ lengths,  // (B,)
    float* __restrict__ out)
{
    const int b      = blockIdx.x;
    const int lane   = threadIdx.x;
    const int len    = lengths[b];
    const int lm1    = len - 1;
    const int lane_c = (lane < K_N) ? lane : (K_N - 1);   // clamp: all addrs valid

    // E row in named scalars (VGPR-resident). Lanes >= K_N compute junk but
    // finite q forever — never readlane'd (k<=46), never stored.
    const float* tr = trans + lane_c * K_N;
#define DECL_E(k) float E##k = __expf(tr[k]);
    REP47(DECL_E)
#undef DECL_E

    const float*  fb = feats + (size_t)b * K_N;
    const size_t  sT = (size_t)B_N * K_N;

    float q = (lane == START_TAG) ? 1.0f : 0.0f;
    float C = 0.0f;

    // Ping-pong prefetch buffers, all statically indexed (registers).
    float f0[8], f1[8];
    #pragma unroll
    for (int i = 0; i < 8; ++i) {
        int r = (i < lm1) ? i : lm1;
        f0[i] = fb[(size_t)r * sT + lane_c];
    }

    #pragma unroll 1
    for (int blk = 0; blk < T_LEN / 16; ++blk) {
        const int t0 = blk * 16;
        // Phase A: prefetch rows t0+8..t0+15 into f1; run steps t0..t0+7 on f0.
        #pragma unroll
        for (int i = 0; i < 8; ++i) {
            int r = t0 + 8 + i; r = (r < lm1) ? r : lm1;
            f1[i] = fb[(size_t)r * sT + lane_c];
        }
        #pragma unroll
        for (int i = 0; i < 8; ++i) STEP(t0 + i, f0[i]);
        // Phase B: prefetch rows t0+16..t0+23 into f0; run steps t0+8..t0+15 on f1.
        #pragma unroll
        for (int i = 0; i < 8; ++i) {
            int r = t0 + 16 + i; r = (r < lm1) ? r : lm1;
            f0[i] = fb[(size_t)r * sT + lane_c];
        }
        #pragma unroll
        for (int i = 0; i < 8; ++i) STEP(t0 + 8 + i, f1[i]);
    }

    // log_z = C + log(q_j) + trans[STOP, j], logsumexp over lanes.
    float v = (lane < K_N && q > 0.0f)
            ? C + __logf(q) + trans[STOP_TAG * K_N + lane] : -INFINITY;
    float mz = v;
    #pragma unroll
    for (int off = 32; off >= 1; off >>= 1)
        mz = fmaxf(mz, __shfl_xor(mz, off));
    float e = __expf(v - mz);
    float se = e;
    #pragma unroll
    for (int off = 32; off >= 1; off >>= 1)
        se += __shfl_xor(se, off);
    float log_z = mz + __logf(se);

    // Gold path score: lanes stripe over t.
    float gsum = 0.0f;
    for (int t = lane; t < len; t += 64) {
        int next = tags[(size_t)b * T_LEN + t];
        int prev = (t == 0) ? START_TAG : tags[(size_t)b * T_LEN + t - 1];
        gsum += trans[next * K_N + prev]
              + fb[(size_t)t * sT + next];
    }
    #pragma unroll
    for (int off = 32; off >= 1; off >>= 1)
        gsum += __shfl_xor(gsum, off);

    if (lane == 0) {
        int last = tags[(size_t)b * T_LEN + len - 1];
        float gold = gsum + trans[STOP_TAG * K_N + last];
        atomicAdd(out, log_z - gold);
    }
}

extern "C" void kernel_launch(void* const* d_in, const int* in_sizes, int n_in,
                              void* d_out, int out_size, void* d_ws, size_t ws_size,
                              hipStream_t stream) {
    const float* feats   = (const float*)d_in[0];
    const float* trans   = (const float*)d_in[1];
    const int*   tags    = (const int*)d_in[2];
    const int*   lengths = (const int*)d_in[3];
    float* out = (float*)d_out;

    hipMemsetAsync(out, 0, sizeof(float) * out_size, stream);
    crf_fused_kernel<<<B_N, 64, 0, stream>>>(feats, trans, tags, lengths, out);
}